// Round 2
// baseline (2223.885 us; speedup 1.0000x reference)
//
#include <hip/hip_runtime.h>
#include <hip/hip_bf16.h>
#include <cstdint>

typedef __hip_bfloat16 bf16;
typedef __hip_bfloat162 bf162;

// ---------- dtype detection ----------
// If x is bf16: halfword[2*i] is element 2i, exponent ~118..134 (normal(0,1)).
// If x is fp32: halfword[2*i] is the LOW mantissa half of float i -> random exponent.
__global__ void detect_kernel(const unsigned short* __restrict__ xr, int* __restrict__ flag) {
  if (threadIdx.x == 0 && blockIdx.x == 0) {
    int pass = 0;
    for (int i = 0; i < 64; ++i) {
      unsigned short h = xr[2 * i];
      int e = (h >> 7) & 0xFF;
      if (e >= 110 && e <= 140) pass++;
    }
    *flag = (pass >= 32) ? 1 : 0;
  }
}

__global__ void convert_kernel(const void* __restrict__ src, float* __restrict__ dst, int n,
                               const int* __restrict__ flag) {
  int i = blockIdx.x * blockDim.x + threadIdx.x;
  if (i >= n) return;
  if (*flag)
    dst[i] = __bfloat162float(((const bf16*)src)[i]);
  else
    dst[i] = ((const float*)src)[i];
}

// ---------- graph preprocessing ----------

__global__ void count_kernel(const int* __restrict__ dst, int* __restrict__ deg, int E) {
  int i = blockIdx.x * blockDim.x + threadIdx.x;
  if (i < E) atomicAdd(&deg[dst[i]], 1);
}

__global__ void dinv_kernel(const int* __restrict__ deg, float* __restrict__ dinv, int n) {
  int i = blockIdx.x * blockDim.x + threadIdx.x;
  if (i < n) dinv[i] = rsqrtf((float)(deg[i] + 1));  // +1 self-loop
}

// single-block exclusive scan over counts -> row_ptr[0..n]
__global__ void scan_kernel(const int* __restrict__ counts, int* __restrict__ row_ptr, int n) {
  __shared__ int sd[1024];
  __shared__ int carry_s;
  int t = threadIdx.x;
  if (t == 0) carry_s = 0;
  __syncthreads();
  for (int base = 0; base < n; base += 1024) {
    int c0 = carry_s;
    int i = base + t;
    int v = (i < n) ? counts[i] : 0;
    sd[t] = v;
    __syncthreads();
    for (int off = 1; off < 1024; off <<= 1) {
      int x = (t >= off) ? sd[t - off] : 0;
      __syncthreads();
      sd[t] += x;
      __syncthreads();
    }
    if (i < n) row_ptr[i] = c0 + sd[t] - v;  // exclusive
    __syncthreads();
    if (t == 0) carry_s = c0 + sd[1023];
    __syncthreads();
  }
  if (t == 0) row_ptr[n] = carry_s;
}

__global__ void fill_kernel(const int* __restrict__ src, const int* __restrict__ dst,
                            const int* __restrict__ row_ptr, int* __restrict__ cursor,
                            int* __restrict__ col, int E) {
  int i = blockIdx.x * blockDim.x + threadIdx.x;
  if (i < E) {
    int d = dst[i];
    int pos = row_ptr[d] + atomicAdd(&cursor[d], 1);
    col[pos] = src[i];
  }
}

// ---------- GEMM: C[M,128] = A[M,K] @ W[K,128] + bias, optional rowscale / relu ----------
// a_dual=1: A dtype depends on *flag (bf16 if 1, fp32 if 0). a_dual=0: A is fp32.
// In-place (C==A) is safe: each block writes only rows it alone reads, after all reads.

template <typename TOUT>
__global__ __launch_bounds__(256) void gemm_kernel(
    const void* __restrict__ A, const float* __restrict__ W, const float* __restrict__ bias,
    TOUT* __restrict__ C, int M, int K, const float* __restrict__ rowscale, int do_relu,
    const int* __restrict__ flag, int a_dual) {
  __shared__ float As[64][33];
  __shared__ float Ws[32][128];
  int abf = a_dual ? flag[0] : 0;
  int t = threadIdx.x;
  int tx = t & 31, ty = t >> 5;
  int row0 = blockIdx.x * 64;
  float acc[8][4];
#pragma unroll
  for (int i = 0; i < 8; ++i)
#pragma unroll
    for (int j = 0; j < 4; ++j) acc[i][j] = 0.f;

  for (int kc = 0; kc < K; kc += 32) {
    for (int u = t; u < 64 * 32; u += 256) {
      int r = u >> 5, k = u & 31;
      int row = row0 + r;
      float v = 0.f;
      if (row < M) {
        size_t idx = (size_t)row * K + kc + k;
        v = abf ? __bfloat162float(((const bf16*)A)[idx]) : ((const float*)A)[idx];
      }
      As[r][k] = v;
    }
    for (int u = t; u < 32 * 128; u += 256) {
      int k = u >> 7, c = u & 127;
      Ws[k][c] = W[(size_t)(kc + k) * 128 + c];
    }
    __syncthreads();
#pragma unroll
    for (int k = 0; k < 32; ++k) {
      float a[8], b[4];
#pragma unroll
      for (int i = 0; i < 8; ++i) a[i] = As[ty * 8 + i][k];
#pragma unroll
      for (int j = 0; j < 4; ++j) b[j] = Ws[k][tx + 32 * j];
#pragma unroll
      for (int i = 0; i < 8; ++i)
#pragma unroll
        for (int j = 0; j < 4; ++j) acc[i][j] = fmaf(a[i], b[j], acc[i][j]);
    }
    __syncthreads();
  }
#pragma unroll
  for (int i = 0; i < 8; ++i) {
    int row = row0 + ty * 8 + i;
    if (row < M) {
      float rs = rowscale ? rowscale[row] : 1.f;
#pragma unroll
      for (int j = 0; j < 4; ++j) {
        int c = tx + 32 * j;
        float v = (acc[i][j] + bias[c]) * rs;
        if (do_relu) v = fmaxf(v, 0.f);
        if constexpr (sizeof(TOUT) == 2)
          C[(size_t)row * 128 + c] = __float2bfloat16(v);
        else
          C[(size_t)row * 128 + c] = v;
      }
    }
  }
}

// ---------- gather: y[d] = relu(dinv[d] * (g[d] + sum_{s in CSR[d]} g[s])) ----------

__global__ __launch_bounds__(256) void gather_kernel(
    const bf16* __restrict__ g, const int* __restrict__ row_ptr, const int* __restrict__ col,
    const float* __restrict__ dinv, float* __restrict__ y, int n) {
  int wave = threadIdx.x >> 6;
  int lane = threadIdx.x & 63;
  int node = blockIdx.x * 4 + wave;
  if (node >= n) return;
  int f = lane * 2;
  const bf162* gp = (const bf162*)g;
  bf162 sv = gp[((size_t)node * 128 + f) >> 1];
  float ax = __bfloat162float(sv.x), ay = __bfloat162float(sv.y);
  int beg = row_ptr[node], end = row_ptr[node + 1];
  for (int e = beg; e < end; ++e) {
    int s = col[e];
    bf162 v = gp[((size_t)s * 128 + f) >> 1];
    ax += __bfloat162float(v.x);
    ay += __bfloat162float(v.y);
  }
  float dv = dinv[node];
  ax = fmaxf(ax * dv, 0.f);
  ay = fmaxf(ay * dv, 0.f);
  *(float2*)(y + (size_t)node * 128 + f) = make_float2(ax, ay);
}

// ---------- fc3 (128->64) + log_softmax fused; output dtype per flag ----------

__global__ __launch_bounds__(256) void fc3_softmax_kernel(
    const float* __restrict__ y, const float* __restrict__ W, const float* __restrict__ b,
    void* __restrict__ out, int n, const int* __restrict__ flag) {
  __shared__ float Wl[128][64];
  __shared__ float bl[64];
  int isbf = flag[0];
  int t = threadIdx.x;
  for (int u = t; u < 128 * 64; u += 256) Wl[u >> 6][u & 63] = W[u];
  if (t < 64) bl[t] = b[t];
  __syncthreads();
  int wave = t >> 6, lane = t & 63;
  for (int r = blockIdx.x * 4 + wave; r < n; r += gridDim.x * 4) {
    const float* yr = y + (size_t)r * 128;
    float acc = bl[lane];
#pragma unroll 8
    for (int k = 0; k < 128; ++k) acc = fmaf(yr[k], Wl[k][lane], acc);
    float m = acc;
#pragma unroll
    for (int off = 32; off > 0; off >>= 1) m = fmaxf(m, __shfl_xor(m, off, 64));
    float ex = __expf(acc - m);
#pragma unroll
    for (int off = 32; off > 0; off >>= 1) ex += __shfl_xor(ex, off, 64);
    float v = acc - m - __logf(ex);
    if (isbf)
      ((bf16*)out)[(size_t)r * 64 + lane] = __float2bfloat16(v);
    else
      ((float*)out)[(size_t)r * 64 + lane] = v;
  }
}

// ---------- launch ----------

extern "C" void kernel_launch(void* const* d_in, const int* in_sizes, int n_in,
                              void* d_out, int out_size, void* d_ws, size_t ws_size,
                              hipStream_t stream) {
  const void* x  = d_in[0];
  const int* ei  = (const int*)d_in[1];

  const int N = in_sizes[0] / 512;
  const int E = in_sizes[1] / 2;
  const int* srcp = ei;
  const int* dstp = ei + E;

  char* ws = (char*)d_ws;
  size_t off = 0;
  auto alloc = [&](size_t bytes) {
    void* p = ws + off;
    off = (off + bytes + 255) & ~(size_t)255;
    return p;
  };
  int*   flag    = (int*)alloc(4);
  int*   deg     = (int*)alloc((size_t)N * 4);
  int*   cursor  = (int*)alloc((size_t)N * 4);
  int*   row_ptr = (int*)alloc((size_t)(N + 1) * 4);
  int*   col     = (int*)alloc((size_t)E * 4);
  float* dinv    = (float*)alloc((size_t)N * 4);
  // fp32 copies of the 12 weight/bias tensors (inputs 2..13)
  float* wcvt[12];
  for (int i = 0; i < 12; ++i) wcvt[i] = (float*)alloc((size_t)in_sizes[2 + i] * 4);
  float* bufA = (float*)alloc((size_t)N * 128 * 4);
  bf16*  gbuf = (bf16*)alloc((size_t)N * 128 * 2);

  const int tb = 256;

  detect_kernel<<<1, 64, 0, stream>>>((const unsigned short*)x, flag);
  for (int i = 0; i < 12; ++i) {
    int n = in_sizes[2 + i];
    convert_kernel<<<(n + tb - 1) / tb, tb, 0, stream>>>(d_in[2 + i], wcvt[i], n, flag);
  }

  hipMemsetAsync(deg, 0, (size_t)N * 4, stream);
  hipMemsetAsync(cursor, 0, (size_t)N * 4, stream);

  count_kernel<<<(E + tb - 1) / tb, tb, 0, stream>>>(dstp, deg, E);
  dinv_kernel<<<(N + tb - 1) / tb, tb, 0, stream>>>(deg, dinv, N);
  scan_kernel<<<1, 1024, 0, stream>>>(deg, row_ptr, N);
  fill_kernel<<<(E + tb - 1) / tb, tb, 0, stream>>>(srcp, dstp, row_ptr, cursor, col, E);

  int gemm_blocks = (N + 63) / 64;
  int gat_blocks  = (N + 3) / 4;

  // conv0: g = (x@W0+b0)*dinv ; y = relu(dinv*(g[d]+sum g[s]))
  gemm_kernel<bf16><<<gemm_blocks, 256, 0, stream>>>(x, wcvt[0], wcvt[1], gbuf, N, 512, dinv, 0, flag, 1);
  gather_kernel<<<gat_blocks, 256, 0, stream>>>(gbuf, row_ptr, col, dinv, bufA, N);
  // conv1
  gemm_kernel<bf16><<<gemm_blocks, 256, 0, stream>>>(bufA, wcvt[2], wcvt[3], gbuf, N, 128, dinv, 0, flag, 0);
  gather_kernel<<<gat_blocks, 256, 0, stream>>>(gbuf, row_ptr, col, dinv, bufA, N);
  // conv2
  gemm_kernel<bf16><<<gemm_blocks, 256, 0, stream>>>(bufA, wcvt[4], wcvt[5], gbuf, N, 128, dinv, 0, flag, 0);
  gather_kernel<<<gat_blocks, 256, 0, stream>>>(gbuf, row_ptr, col, dinv, bufA, N);
  // fc1, fc2 (relu, in-place)
  gemm_kernel<float><<<gemm_blocks, 256, 0, stream>>>(bufA, wcvt[6], wcvt[7], bufA, N, 128, nullptr, 1, flag, 0);
  gemm_kernel<float><<<gemm_blocks, 256, 0, stream>>>(bufA, wcvt[8], wcvt[9], bufA, N, 128, nullptr, 1, flag, 0);
  // fc3 + log_softmax
  fc3_softmax_kernel<<<gat_blocks, 256, 0, stream>>>(bufA, wcvt[10], wcvt[11], d_out, N, flag);
}

// Round 3
// 1291.429 us; speedup vs baseline: 1.7220x; 1.7220x over previous
//
#include <hip/hip_runtime.h>
#include <hip/hip_bf16.h>
#include <cstdint>

typedef __hip_bfloat16 bf16;
typedef __hip_bfloat162 bf162;
typedef __bf16 bf16x8 __attribute__((ext_vector_type(8)));
typedef float f32x4 __attribute__((ext_vector_type(4)));

// ---------- dtype detection ----------
// If x is bf16: halfword[2*i] is element 2i, exponent ~118..134 (normal(0,1)).
// If x is fp32: halfword[2*i] is the LOW mantissa half of float i -> random exponent.
__global__ void detect_kernel(const unsigned short* __restrict__ xr, int* __restrict__ flag) {
  if (threadIdx.x == 0 && blockIdx.x == 0) {
    int pass = 0;
    for (int i = 0; i < 64; ++i) {
      unsigned short h = xr[2 * i];
      int e = (h >> 7) & 0xFF;
      if (e >= 110 && e <= 140) pass++;
    }
    *flag = (pass >= 32) ? 1 : 0;
  }
}

// src (bf16 or fp32 per flag) -> fp32
__global__ void convert_kernel(const void* __restrict__ src, float* __restrict__ dst, int n,
                               const int* __restrict__ flag) {
  int i = blockIdx.x * blockDim.x + threadIdx.x;
  if (i >= n) return;
  dst[i] = (*flag) ? __bfloat162float(((const bf16*)src)[i]) : ((const float*)src)[i];
}

// W[fi][fo] (bf16 or fp32 per flag) -> Wt[fo][fi] bf16
__global__ void transpose_w_kernel(const void* __restrict__ src, __bf16* __restrict__ dst,
                                   int fi, int fo, const int* __restrict__ flag) {
  int i = blockIdx.x * blockDim.x + threadIdx.x;
  if (i >= fi * fo) return;
  int k = i / fo, n = i % fo;
  float v = (*flag) ? __bfloat162float(((const bf16*)src)[i]) : ((const float*)src)[i];
  dst[(size_t)n * fi + k] = (__bf16)v;
}

// ---------- graph preprocessing ----------

__global__ void count_kernel(const int* __restrict__ dst, int* __restrict__ deg, int E) {
  int i = blockIdx.x * blockDim.x + threadIdx.x;
  if (i < E) atomicAdd(&deg[dst[i]], 1);
}

__global__ void dinv_kernel(const int* __restrict__ deg, float* __restrict__ dinv, int n) {
  int i = blockIdx.x * blockDim.x + threadIdx.x;
  if (i < n) dinv[i] = rsqrtf((float)(deg[i] + 1));  // +1 self-loop
}

// hierarchical exclusive scan: per-block scan + block sums
__global__ void scan_block_kernel(const int* __restrict__ counts, int* __restrict__ excl,
                                  int* __restrict__ bsum, int n) {
  __shared__ int sd[1024];
  int t = threadIdx.x;
  int i = blockIdx.x * 1024 + t;
  int v = (i < n) ? counts[i] : 0;
  sd[t] = v;
  __syncthreads();
  for (int off = 1; off < 1024; off <<= 1) {
    int x = (t >= off) ? sd[t - off] : 0;
    __syncthreads();
    sd[t] += x;
    __syncthreads();
  }
  if (i < n) excl[i] = sd[t] - v;
  if (t == 1023) bsum[blockIdx.x] = sd[1023];
}

// scan the (<=1024) block sums; writes total to row_ptr[n]
__global__ void scan_sums_kernel(int* __restrict__ bsum, int nb, int* __restrict__ row_ptr, int n) {
  __shared__ int sd[1024];
  int t = threadIdx.x;
  int v = (t < nb) ? bsum[t] : 0;
  sd[t] = v;
  __syncthreads();
  for (int off = 1; off < 1024; off <<= 1) {
    int x = (t >= off) ? sd[t - off] : 0;
    __syncthreads();
    sd[t] += x;
    __syncthreads();
  }
  if (t < nb) bsum[t] = sd[t] - v;  // exclusive
  if (t == 1023) row_ptr[n] = sd[1023];
}

__global__ void scan_add_kernel(int* __restrict__ excl, const int* __restrict__ bsum, int n) {
  int i = blockIdx.x * blockDim.x + threadIdx.x;
  if (i < n) excl[i] += bsum[i >> 10];
}

__global__ void fill_kernel(const int* __restrict__ src, const int* __restrict__ dst,
                            const int* __restrict__ row_ptr, int* __restrict__ cursor,
                            int* __restrict__ col, int E) {
  int i = blockIdx.x * blockDim.x + threadIdx.x;
  if (i < E) {
    int d = dst[i];
    int pos = row_ptr[d] + atomicAdd(&cursor[d], 1);
    col[pos] = src[i];
  }
}

// ---------- MFMA GEMM: C[M,128] = A[M,K] @ Wt^T + bias, optional rowscale / relu ----------
// No LDS: N=128 means A rows have zero cross-block reuse; Wt is L2-resident.
// Each wave: 64x64 via 4x4 grid of 16x16x32 MFMA; block = 4 waves = 128x128.
// a-frag: A[m=lane&15][k=quad*8+j] ; b-frag: Wt[n=lane&15-row][k=quad*8+j] (Wt pre-transposed)
// C/D: row=quad*4+reg, col=lane&15 [m89/m91].

__global__ __launch_bounds__(256) void gemm_mfma_kernel(
    const void* __restrict__ Ain, const __bf16* __restrict__ Bt,  // Bt: [128][K]
    const float* __restrict__ bias, bf16* __restrict__ C,
    int M, int K, const float* __restrict__ rowscale, int do_relu,
    const int* __restrict__ flag, int a_dual) {
  int abf = a_dual ? flag[0] : 1;  // 1 => A is bf16
  int t = threadIdx.x;
  int wave = t >> 6, lane = t & 63;
  int l15 = lane & 15, quad = lane >> 4;
  int wm = wave >> 1, wn = wave & 1;
  int rowbase = blockIdx.x * 128 + wm * 64;
  int colbase = wn * 64;
  const __bf16* Ab = (const __bf16*)Ain;
  const float* Af = (const float*)Ain;

  f32x4 acc[4][4];
#pragma unroll
  for (int mt = 0; mt < 4; ++mt)
#pragma unroll
    for (int nt = 0; nt < 4; ++nt) acc[mt][nt] = (f32x4){0.f, 0.f, 0.f, 0.f};

  int arow[4];
#pragma unroll
  for (int mt = 0; mt < 4; ++mt) {
    int r = rowbase + mt * 16 + l15;
    arow[mt] = (r < M) ? r : (M - 1);  // clamp; garbage rows masked at store
  }

  for (int kc = 0; kc < K; kc += 32) {
    int ko = kc + quad * 8;
    bf16x8 a[4], b[4];
    if (abf) {
#pragma unroll
      for (int mt = 0; mt < 4; ++mt)
        a[mt] = *(const bf16x8*)(Ab + (size_t)arow[mt] * K + ko);
    } else {
#pragma unroll
      for (int mt = 0; mt < 4; ++mt) {
        const float* p = Af + (size_t)arow[mt] * K + ko;
#pragma unroll
        for (int j = 0; j < 8; ++j) a[mt][j] = (__bf16)p[j];
      }
    }
#pragma unroll
    for (int nt = 0; nt < 4; ++nt)
      b[nt] = *(const bf16x8*)(Bt + (size_t)(colbase + nt * 16 + l15) * K + ko);
#pragma unroll
    for (int mt = 0; mt < 4; ++mt)
#pragma unroll
      for (int nt = 0; nt < 4; ++nt)
        acc[mt][nt] = __builtin_amdgcn_mfma_f32_16x16x32_bf16(a[mt], b[nt], acc[mt][nt], 0, 0, 0);
  }

#pragma unroll
  for (int mt = 0; mt < 4; ++mt) {
    int r0 = rowbase + mt * 16 + quad * 4;
#pragma unroll
    for (int nt = 0; nt < 4; ++nt) {
      int c = colbase + nt * 16 + l15;
      float bs = bias[c];
#pragma unroll
      for (int i = 0; i < 4; ++i) {
        int r = r0 + i;
        if (r < M) {
          float v = acc[mt][nt][i] + bs;
          if (rowscale) v *= rowscale[r];
          if (do_relu) v = fmaxf(v, 0.f);
          C[(size_t)r * 128 + c] = __float2bfloat16(v);
        }
      }
    }
  }
}

// ---------- gather: y[d] = relu(dinv[d] * (g[d] + sum_{s in CSR[d]} g[s])) ----------

__global__ __launch_bounds__(256) void gather_kernel(
    const bf16* __restrict__ g, const int* __restrict__ row_ptr, const int* __restrict__ col,
    const float* __restrict__ dinv, bf16* __restrict__ y, int n) {
  int wave = threadIdx.x >> 6;
  int lane = threadIdx.x & 63;
  int node = blockIdx.x * 4 + wave;
  if (node >= n) return;
  const bf162* gp = (const bf162*)g;
  bf162 sv = gp[(size_t)node * 64 + lane];
  float ax = __bfloat162float(sv.x), ay = __bfloat162float(sv.y);
  int beg = row_ptr[node], end = row_ptr[node + 1];
  for (int e = beg; e < end; ++e) {
    int s = col[e];
    bf162 v = gp[(size_t)s * 64 + lane];
    ax += __bfloat162float(v.x);
    ay += __bfloat162float(v.y);
  }
  float dv = dinv[node];
  ax = fmaxf(ax * dv, 0.f);
  ay = fmaxf(ay * dv, 0.f);
  bf162 o;
  o.x = __float2bfloat16(ax);
  o.y = __float2bfloat16(ay);
  ((bf162*)y)[(size_t)node * 64 + lane] = o;
}

// ---------- fc3 (128->64) + log_softmax fused; output dtype per flag ----------

__global__ __launch_bounds__(256) void fc3_softmax_kernel(
    const bf16* __restrict__ y, const float* __restrict__ W, const float* __restrict__ b,
    void* __restrict__ out, int n, const int* __restrict__ flag) {
  __shared__ float Wl[128][64];
  __shared__ float bl[64];
  int isbf = flag[0];
  int t = threadIdx.x;
  for (int u = t; u < 128 * 64; u += 256) Wl[u >> 6][u & 63] = W[u];
  if (t < 64) bl[t] = b[t];
  __syncthreads();
  int wave = t >> 6, lane = t & 63;
  for (int r = blockIdx.x * 4 + wave; r < n; r += gridDim.x * 4) {
    const bf16* yr = y + (size_t)r * 128;
    float acc = bl[lane];
#pragma unroll 8
    for (int k = 0; k < 128; ++k) acc = fmaf(__bfloat162float(yr[k]), Wl[k][lane], acc);
    float m = acc;
#pragma unroll
    for (int off = 32; off > 0; off >>= 1) m = fmaxf(m, __shfl_xor(m, off, 64));
    float ex = __expf(acc - m);
#pragma unroll
    for (int off = 32; off > 0; off >>= 1) ex += __shfl_xor(ex, off, 64);
    float v = acc - m - __logf(ex);
    if (isbf)
      ((bf16*)out)[(size_t)r * 64 + lane] = __float2bfloat16(v);
    else
      ((float*)out)[(size_t)r * 64 + lane] = v;
  }
}

// ---------- launch ----------

extern "C" void kernel_launch(void* const* d_in, const int* in_sizes, int n_in,
                              void* d_out, int out_size, void* d_ws, size_t ws_size,
                              hipStream_t stream) {
  const void* x = d_in[0];
  const int* ei = (const int*)d_in[1];

  const int N = in_sizes[0] / 512;
  const int E = in_sizes[1] / 2;
  const int* srcp = ei;
  const int* dstp = ei + E;

  char* ws = (char*)d_ws;
  size_t off = 0;
  auto alloc = [&](size_t bytes) {
    void* p = ws + off;
    off = (off + bytes + 255) & ~(size_t)255;
    return p;
  };
  int*    flag    = (int*)alloc(4);
  int*    deg     = (int*)alloc((size_t)N * 4);
  int*    cursor  = (int*)alloc((size_t)N * 4);
  int*    row_ptr = (int*)alloc((size_t)(N + 1) * 4);
  int*    col     = (int*)alloc((size_t)E * 4);
  float*  dinv    = (float*)alloc((size_t)N * 4);
  int*    bsum    = (int*)alloc(1024 * 4);
  __bf16* W0t     = (__bf16*)alloc((size_t)512 * 128 * 2);
  __bf16* W1t     = (__bf16*)alloc((size_t)128 * 128 * 2);
  __bf16* W2t     = (__bf16*)alloc((size_t)128 * 128 * 2);
  __bf16* fc1t    = (__bf16*)alloc((size_t)128 * 128 * 2);
  __bf16* fc2t    = (__bf16*)alloc((size_t)128 * 128 * 2);
  float*  fc3wf   = (float*)alloc((size_t)128 * 64 * 4);
  float*  b0f     = (float*)alloc(128 * 4);
  float*  b1f     = (float*)alloc(128 * 4);
  float*  b2f     = (float*)alloc(128 * 4);
  float*  fc1bf   = (float*)alloc(128 * 4);
  float*  fc2bf   = (float*)alloc(128 * 4);
  float*  fc3bf   = (float*)alloc(64 * 4);
  bf16*   gbuf    = (bf16*)alloc((size_t)N * 128 * 2);
  bf16*   ybuf    = (bf16*)alloc((size_t)N * 128 * 2);

  const int tb = 256;

  detect_kernel<<<1, 64, 0, stream>>>((const unsigned short*)x, flag);

  transpose_w_kernel<<<(512 * 128 + tb - 1) / tb, tb, 0, stream>>>(d_in[2], W0t, 512, 128, flag);
  transpose_w_kernel<<<(128 * 128 + tb - 1) / tb, tb, 0, stream>>>(d_in[4], W1t, 128, 128, flag);
  transpose_w_kernel<<<(128 * 128 + tb - 1) / tb, tb, 0, stream>>>(d_in[6], W2t, 128, 128, flag);
  transpose_w_kernel<<<(128 * 128 + tb - 1) / tb, tb, 0, stream>>>(d_in[8], fc1t, 128, 128, flag);
  transpose_w_kernel<<<(128 * 128 + tb - 1) / tb, tb, 0, stream>>>(d_in[10], fc2t, 128, 128, flag);
  convert_kernel<<<1, 128, 0, stream>>>(d_in[3], b0f, 128, flag);
  convert_kernel<<<1, 128, 0, stream>>>(d_in[5], b1f, 128, flag);
  convert_kernel<<<1, 128, 0, stream>>>(d_in[7], b2f, 128, flag);
  convert_kernel<<<1, 128, 0, stream>>>(d_in[9], fc1bf, 128, flag);
  convert_kernel<<<1, 128, 0, stream>>>(d_in[11], fc2bf, 128, flag);
  convert_kernel<<<(128 * 64 + tb - 1) / tb, tb, 0, stream>>>(d_in[12], fc3wf, 128 * 64, flag);
  convert_kernel<<<1, 64, 0, stream>>>(d_in[13], fc3bf, 64, flag);

  hipMemsetAsync(deg, 0, (size_t)N * 4, stream);
  hipMemsetAsync(cursor, 0, (size_t)N * 4, stream);

  count_kernel<<<(E + tb - 1) / tb, tb, 0, stream>>>(dstp, deg, E);
  dinv_kernel<<<(N + tb - 1) / tb, tb, 0, stream>>>(deg, dinv, N);
  int nb = (N + 1023) / 1024;
  scan_block_kernel<<<nb, 1024, 0, stream>>>(deg, row_ptr, bsum, N);
  scan_sums_kernel<<<1, 1024, 0, stream>>>(bsum, nb, row_ptr, N);
  scan_add_kernel<<<(N + tb - 1) / tb, tb, 0, stream>>>(row_ptr, bsum, N);
  fill_kernel<<<(E + tb - 1) / tb, tb, 0, stream>>>(srcp, dstp, row_ptr, cursor, col, E);

  int gemm_blocks = (N + 127) / 128;
  int gat_blocks = (N + 3) / 4;

  // conv0: g = (x@W0+b0)*dinv ; y = relu(dinv*(g[d]+sum g[s]))
  gemm_mfma_kernel<<<gemm_blocks, 256, 0, stream>>>(x, W0t, b0f, gbuf, N, 512, dinv, 0, flag, 1);
  gather_kernel<<<gat_blocks, 256, 0, stream>>>(gbuf, row_ptr, col, dinv, ybuf, N);
  // conv1
  gemm_mfma_kernel<<<gemm_blocks, 256, 0, stream>>>(ybuf, W1t, b1f, gbuf, N, 128, dinv, 0, flag, 0);
  gather_kernel<<<gat_blocks, 256, 0, stream>>>(gbuf, row_ptr, col, dinv, ybuf, N);
  // conv2
  gemm_mfma_kernel<<<gemm_blocks, 256, 0, stream>>>(ybuf, W2t, b2f, gbuf, N, 128, dinv, 0, flag, 0);
  gather_kernel<<<gat_blocks, 256, 0, stream>>>(gbuf, row_ptr, col, dinv, ybuf, N);
  // fc1 (ybuf -> gbuf), fc2 (gbuf -> ybuf), relu
  gemm_mfma_kernel<<<gemm_blocks, 256, 0, stream>>>(ybuf, fc1t, fc1bf, gbuf, N, 128, nullptr, 1, flag, 0);
  gemm_mfma_kernel<<<gemm_blocks, 256, 0, stream>>>(gbuf, fc2t, fc2bf, ybuf, N, 128, nullptr, 1, flag, 0);
  // fc3 + log_softmax
  fc3_softmax_kernel<<<gat_blocks, 256, 0, stream>>>(ybuf, fc3wf, fc3bf, d_out, N, flag);
}